// Round 1
// baseline (8103.444 us; speedup 1.0000x reference)
//
#include <hip/hip_runtime.h>
#include <hip/hip_bf16.h>

// HGT conv, f32 pipeline.
// ws layout (floats): q[N*128] | kr[N*128] | vr[N*128] | t_agg[N*128] | ex[E*8] | s[N*8]
//   = 4*6.4M + 4.0M + 0.4M = 30.0M floats = 120 MB
constexpr int NN  = 50000;
constexpr int EE  = 500000;
constexpr int CF  = 128;   // IN == OUT
constexpr int NH  = 8;
constexpr int DKC = 16;

__device__ __forceinline__ void atomAddF(float* p, float v) {
#if defined(__HIP_DEVICE_COMPILE__)
  unsafeAtomicAdd(p, v);   // native global_atomic_add_f32 on gfx950
#else
  (void)p; (void)v;
#endif
}

// One block (128 threads) per node: k/q/v GEMM + per-head DKxDK relation transforms.
__global__ __launch_bounds__(128)
void k_qkv(const float* __restrict__ h,
           const float* __restrict__ Wk, const float* __restrict__ bk,
           const float* __restrict__ Wq, const float* __restrict__ bq,
           const float* __restrict__ Wv, const float* __restrict__ bv,
           const float* __restrict__ rel_att, const float* __restrict__ rel_msg,
           float* __restrict__ q_out, float* __restrict__ kr_out,
           float* __restrict__ vr_out, int rel, int write_q) {
  __shared__ float hs[CF], ks[CF], vs[CF];
  const int n = blockIdx.x;
  const int t = threadIdx.x;
  hs[t] = h[(size_t)n * CF + t];
  __syncthreads();
  float aK = bk[t], aQ = bq[t], aV = bv[t];
#pragma unroll 8
  for (int j = 0; j < CF; ++j) {
    const float hv = hs[j];
    aK = fmaf(hv, Wk[j * CF + t], aK);
    aQ = fmaf(hv, Wq[j * CF + t], aQ);
    aV = fmaf(hv, Wv[j * CF + t], aV);
  }
  ks[t] = aK; vs[t] = aV;
  if (write_q) q_out[(size_t)n * CF + t] = aQ;
  __syncthreads();
  const int hh = t >> 4, d = t & 15;
  const float* A = rel_att + ((rel * NH + hh) * DKC * DKC) + d;  // [j][d], stride DKC over j
  const float* M = rel_msg + ((rel * NH + hh) * DKC * DKC) + d;
  float kv = 0.f, vv = 0.f;
#pragma unroll
  for (int j = 0; j < DKC; ++j) {
    kv = fmaf(ks[hh * DKC + j], A[j * DKC], kv);
    vv = fmaf(vs[hh * DKC + j], M[j * DKC], vv);
  }
  kr_out[(size_t)n * CF + t] = kv;
  vr_out[(size_t)n * CF + t] = vv;
}

// One thread per (edge, head): score = (q[dst,h,:] . kr[src,h,:]) * pri / sqrt(DK).
// Stores ex = exp(score) (max-subtraction skipped: |score| bounded ~7, softmax identical),
// accumulates denominator s[dst,h].
__global__ __launch_bounds__(256)
void k_score_sum(const int* __restrict__ src, const int* __restrict__ dst,
                 const float* __restrict__ q, const float* __restrict__ kr,
                 const float* __restrict__ rel_pri, int rel,
                 float* __restrict__ ex, float* __restrict__ s) {
  const int gid = blockIdx.x * 256 + threadIdx.x;
  if (gid >= EE * NH) return;
  const int e = gid >> 3, hh = gid & 7;
  const int sn = src[e], dn = dst[e];
  const float4* qp = (const float4*)(q + (size_t)dn * CF + hh * DKC);
  const float4* kp = (const float4*)(kr + (size_t)sn * CF + hh * DKC);
  float acc = 0.f;
#pragma unroll
  for (int i = 0; i < 4; ++i) {
    const float4 a = qp[i], b = kp[i];
    acc += a.x * b.x + a.y * b.y + a.z * b.z + a.w * b.w;
  }
  const float sc = acc * rel_pri[rel * NH + hh] * 0.25f;  // 1/sqrt(16)
  const float e_s = __expf(sc);
  ex[gid] = e_s;
  atomAddF(s + (size_t)dn * NH + hh, e_s);
}

// One thread per (edge, head): attn = ex/s[dst]; scatter vr[src]*attn into t_agg[dst].
__global__ __launch_bounds__(256)
void k_scatter(const int* __restrict__ src, const int* __restrict__ dst,
               const float* __restrict__ ex, const float* __restrict__ s,
               const float* __restrict__ vr, float* __restrict__ t_agg) {
  const int gid = blockIdx.x * 256 + threadIdx.x;
  if (gid >= EE * NH) return;
  const int e = gid >> 3, hh = gid & 7;
  const int sn = src[e], dn = dst[e];
  const float attn = ex[gid] / s[(size_t)dn * NH + hh];
  const float4* vp = (const float4*)(vr + (size_t)sn * CF + hh * DKC);
  float* tp = t_agg + (size_t)dn * CF + hh * DKC;
#pragma unroll
  for (int i = 0; i < 4; ++i) {
    const float4 v = vp[i];
    atomAddF(tp + 4 * i + 0, v.x * attn);
    atomAddF(tp + 4 * i + 1, v.y * attn);
    atomAddF(tp + 4 * i + 2, v.z * attn);
    atomAddF(tp + 4 * i + 3, v.w * attn);
  }
}

// One block per node: exact GELU on t_agg row, GEMM with Wa, skip blend.
__global__ __launch_bounds__(128)
void k_final(const float* __restrict__ t_agg, const float* __restrict__ h,
             const float* __restrict__ Wa, const float* __restrict__ ba,
             const float* __restrict__ skip, float* __restrict__ out) {
  __shared__ float ts[CF];
  const int n = blockIdx.x, t = threadIdx.x;
  const float x = t_agg[(size_t)n * CF + t];
  ts[t] = 0.5f * x * (1.f + erff(x * 0.70710678118f));
  __syncthreads();
  float acc = ba[t];
#pragma unroll 8
  for (int j = 0; j < CF; ++j) acc = fmaf(ts[j], Wa[j * CF + t], acc);
  const float alpha = 1.f / (1.f + __expf(-skip[0]));
  out[(size_t)n * CF + t] = acc * alpha + h[(size_t)n * CF + t] * (1.f - alpha);
}

extern "C" void kernel_launch(void* const* d_in, const int* in_sizes, int n_in,
                              void* d_out, int out_size, void* d_ws, size_t ws_size,
                              hipStream_t stream) {
  const float* h   = (const float*)d_in[0];
  const int* srcA[2] = {(const int*)d_in[1], (const int*)d_in[3]};
  const int* dstA[2] = {(const int*)d_in[2], (const int*)d_in[4]};
  const float* Wk = (const float*)d_in[5],  *bk = (const float*)d_in[6];
  const float* Wq = (const float*)d_in[7],  *bq = (const float*)d_in[8];
  const float* Wv = (const float*)d_in[9],  *bv = (const float*)d_in[10];
  const float* Wa = (const float*)d_in[11], *ba = (const float*)d_in[12];
  const float* rel_att = (const float*)d_in[13];
  const float* rel_msg = (const float*)d_in[14];
  const float* rel_pri = (const float*)d_in[15];
  const float* skip    = (const float*)d_in[16];
  float* out = (float*)d_out;

  const size_t NC = (size_t)NN * CF;
  float* q     = (float*)d_ws;
  float* kr    = q + NC;
  float* vr    = kr + NC;
  float* t_agg = vr + NC;
  float* ex    = t_agg + NC;
  float* s     = ex + (size_t)EE * NH;

  hipMemsetAsync(t_agg, 0, NC * sizeof(float), stream);

  const int egrid = (EE * NH + 255) / 256;
  for (int rel = 0; rel < 2; ++rel) {
    hipMemsetAsync(s, 0, (size_t)NN * NH * sizeof(float), stream);
    k_qkv<<<NN, 128, 0, stream>>>(h, Wk, bk, Wq, bq, Wv, bv, rel_att, rel_msg,
                                  q, kr, vr, rel, rel == 0 ? 1 : 0);
    k_score_sum<<<egrid, 256, 0, stream>>>(srcA[rel], dstA[rel], q, kr,
                                           rel_pri, rel, ex, s);
    k_scatter<<<egrid, 256, 0, stream>>>(srcA[rel], dstA[rel], ex, s, vr, t_agg);
  }
  k_final<<<NN, 128, 0, stream>>>(t_agg, h, Wa, ba, skip, out);
}

// Round 2
// 1145.259 us; speedup vs baseline: 7.0756x; 7.0756x over previous
//
#include <hip/hip_runtime.h>
#include <hip/hip_bf16.h>

// HGT conv: CSR-gather restructure (no float atomics).
// ws (floats): q[N*128] | k[N*128] | v[N*128]
// then (ints): rowptr0[50048] rowptr1[50048] esrc0[E] esrc1[E] deg[N] cursor[N] bsum[64]
constexpr int NN  = 50000;
constexpr int EE  = 500000;
constexpr int CF  = 128;
constexpr int NH  = 8;
constexpr int DKC = 16;

// ---- base projections: one block per node, q/k/v = h@W + b -------------------
__global__ __launch_bounds__(128)
void k_base(const float* __restrict__ h,
            const float* __restrict__ Wk, const float* __restrict__ bk,
            const float* __restrict__ Wq, const float* __restrict__ bq,
            const float* __restrict__ Wv, const float* __restrict__ bv,
            float* __restrict__ q_out, float* __restrict__ k_out,
            float* __restrict__ v_out) {
  __shared__ float hs[CF];
  const int n = blockIdx.x, t = threadIdx.x;
  hs[t] = h[(size_t)n * CF + t];
  __syncthreads();
  float aK = bk[t], aQ = bq[t], aV = bv[t];
#pragma unroll 8
  for (int j = 0; j < CF; ++j) {
    const float hv = hs[j];
    aK = fmaf(hv, Wk[j * CF + t], aK);
    aQ = fmaf(hv, Wq[j * CF + t], aQ);
    aV = fmaf(hv, Wv[j * CF + t], aV);
  }
  q_out[(size_t)n * CF + t] = aQ;
  k_out[(size_t)n * CF + t] = aK;
  v_out[(size_t)n * CF + t] = aV;
}

// ---- CSR build ---------------------------------------------------------------
__global__ __launch_bounds__(256)
void k_count(const int* __restrict__ dst, int* __restrict__ deg) {
  const int e = blockIdx.x * 256 + threadIdx.x;
  if (e < EE) atomicAdd(&deg[dst[e]], 1);
}

__global__ __launch_bounds__(1024)
void k_scan1(const int* __restrict__ deg, int* __restrict__ rowptr,
             int* __restrict__ bsum, int n) {
  __shared__ int wsum[16];
  const int i = blockIdx.x * 1024 + threadIdx.x;
  const int lane = threadIdx.x & 63, w = threadIdx.x >> 6;
  const int vdeg = (i < n) ? deg[i] : 0;
  int sc = vdeg;
  for (int off = 1; off < 64; off <<= 1) {
    const int x = __shfl_up(sc, off, 64);
    if (lane >= off) sc += x;
  }
  if (lane == 63) wsum[w] = sc;
  __syncthreads();
  if (threadIdx.x < 16) {
    const int x = wsum[threadIdx.x];
    int s2 = x;
    for (int off = 1; off < 16; off <<= 1) {
      const int y = __shfl_up(s2, off, 64);
      if ((int)threadIdx.x >= off) s2 += y;
    }
    wsum[threadIdx.x] = s2 - x;           // exclusive wave offsets
    if (threadIdx.x == 15) bsum[blockIdx.x] = s2;  // block total
  }
  __syncthreads();
  if (i < n) rowptr[i] = sc - vdeg + wsum[w];      // local exclusive
}

__global__ void k_scan2(int* __restrict__ bsum, int nb) {
  const int t = threadIdx.x;
  const int vv = (t < nb) ? bsum[t] : 0;
  int sc = vv;
  for (int off = 1; off < 64; off <<= 1) {
    const int x = __shfl_up(sc, off, 64);
    if (t >= off) sc += x;
  }
  if (t < nb) bsum[t] = sc - vv;          // exclusive
}

__global__ __launch_bounds__(1024)
void k_scan3(int* __restrict__ rowptr, const int* __restrict__ bsum,
             int* __restrict__ cursor, int n, int total) {
  const int i = blockIdx.x * 1024 + threadIdx.x;
  if (i < n) {
    const int vv = rowptr[i] + bsum[blockIdx.x];
    rowptr[i] = vv;
    cursor[i] = vv;
  } else if (i == n) {
    rowptr[n] = total;
  }
}

__global__ __launch_bounds__(256)
void k_fill(const int* __restrict__ src, const int* __restrict__ dst,
            int* __restrict__ cursor, int* __restrict__ esrc) {
  const int e = blockIdx.x * 256 + threadIdx.x;
  if (e < EE) {
    const int pos = atomicAdd(&cursor[dst[e]], 1);
    esrc[pos] = src[e];
  }
}

// ---- fused attention aggregate + GELU + Wa GEMV + skip blend -----------------
// One block (128 thr) per dst node. Thread t: head hh=t>>4, dim d=t&15.
__global__ __launch_bounds__(128)
void k_agg(const float* __restrict__ q, const float* __restrict__ kk,
           const float* __restrict__ vv_g,
           const int* __restrict__ rowptr0, const int* __restrict__ esrc0,
           const int* __restrict__ rowptr1, const int* __restrict__ esrc1,
           const float* __restrict__ rel_att, const float* __restrict__ rel_msg,
           const float* __restrict__ rel_pri,
           const float* __restrict__ h, const float* __restrict__ Wa,
           const float* __restrict__ ba, const float* __restrict__ skip,
           float* __restrict__ out) {
  __shared__ float ts[CF];
  const int n = blockIdx.x, t = threadIdx.x;
  const int hh = t >> 4;
  const int d = t & 15;
  const int gbase = (t & 63) & 48;  // 16-group base lane within wave
  const float qv = q[(size_t)n * CF + t];
  float acc = 0.f;

  for (int rel = 0; rel < 2; ++rel) {
    const int* rowptr = rel ? rowptr1 : rowptr0;
    const int* esrc   = rel ? esrc1 : esrc0;
    // hoist transform columns: att[rel][hh][j][d], j=0..15
    float attc[DKC], msgc[DKC];
    const float* A = rel_att + ((rel * NH + hh) * DKC * DKC) + d;
    const float* M = rel_msg + ((rel * NH + hh) * DKC * DKC) + d;
#pragma unroll
    for (int j = 0; j < DKC; ++j) { attc[j] = A[j * DKC]; msgc[j] = M[j * DKC]; }
    const float pri = rel_pri[rel * NH + hh] * 0.25f;  // 1/sqrt(DK)

    const int e0 = rowptr[n], e1 = rowptr[n + 1];
    float racc = 0.f, sden = 0.f;
    float kv = 0.f, vv = 0.f;
    if (e0 < e1) {
      const int sn = esrc[e0];
      kv = kk[(size_t)sn * CF + t];
      vv = vv_g[(size_t)sn * CF + t];
    }
    for (int e = e0; e < e1; ++e) {
      const float kvc = kv, vvc = vv;
      if (e + 1 < e1) {  // prefetch next edge's rows
        const int sn2 = esrc[e + 1];
        kv = kk[(size_t)sn2 * CF + t];
        vv = vv_g[(size_t)sn2 * CF + t];
      }
      float krt = 0.f, vrt = 0.f;
#pragma unroll
      for (int j = 0; j < DKC; ++j) {
        krt = fmaf(__shfl(kvc, gbase + j, 64), attc[j], krt);
        vrt = fmaf(__shfl(vvc, gbase + j, 64), msgc[j], vrt);
      }
      float sc = qv * krt;
      sc += __shfl_xor(sc, 1, 64);
      sc += __shfl_xor(sc, 2, 64);
      sc += __shfl_xor(sc, 4, 64);
      sc += __shfl_xor(sc, 8, 64);
      const float ex = __expf(sc * pri);
      sden += ex;
      racc = fmaf(vrt, ex, racc);
    }
    if (sden > 0.f) acc += racc / sden;
  }

  // exact GELU, Wa GEMV, skip blend
  ts[t] = 0.5f * acc * (1.f + erff(acc * 0.70710678118f));
  __syncthreads();
  float o = ba[t];
#pragma unroll 8
  for (int j = 0; j < CF; ++j) o = fmaf(ts[j], Wa[j * CF + t], o);
  const float alpha = 1.f / (1.f + __expf(-skip[0]));
  out[(size_t)n * CF + t] = o * alpha + h[(size_t)n * CF + t] * (1.f - alpha);
}

extern "C" void kernel_launch(void* const* d_in, const int* in_sizes, int n_in,
                              void* d_out, int out_size, void* d_ws, size_t ws_size,
                              hipStream_t stream) {
  const float* h = (const float*)d_in[0];
  const int* srcA[2] = {(const int*)d_in[1], (const int*)d_in[3]};
  const int* dstA[2] = {(const int*)d_in[2], (const int*)d_in[4]};
  const float* Wk = (const float*)d_in[5],  *bk = (const float*)d_in[6];
  const float* Wq = (const float*)d_in[7],  *bq = (const float*)d_in[8];
  const float* Wv = (const float*)d_in[9],  *bv = (const float*)d_in[10];
  const float* Wa = (const float*)d_in[11], *ba = (const float*)d_in[12];
  const float* rel_att = (const float*)d_in[13];
  const float* rel_msg = (const float*)d_in[14];
  const float* rel_pri = (const float*)d_in[15];
  const float* skip    = (const float*)d_in[16];
  float* out = (float*)d_out;

  const size_t NC = (size_t)NN * CF;
  float* q = (float*)d_ws;
  float* kkp = q + NC;
  float* vvp = kkp + NC;
  int* ip = (int*)(vvp + NC);
  int* rowptr[2] = {ip, ip + 50048};
  int* esrc[2]   = {ip + 2 * 50048, ip + 2 * 50048 + EE};
  int* deg    = ip + 2 * 50048 + 2 * EE;
  int* cursor = deg + NN;
  int* bsum   = cursor + NN;

  k_base<<<NN, 128, 0, stream>>>(h, Wk, bk, Wq, bq, Wv, bv, q, kkp, vvp);

  const int egrid = (EE + 255) / 256;
  const int nb = (NN + 1023) / 1024;          // 49
  const int nb3 = (NN + 1 + 1023) / 1024;     // covers i==NN
  for (int rel = 0; rel < 2; ++rel) {
    hipMemsetAsync(deg, 0, NN * sizeof(int), stream);
    k_count<<<egrid, 256, 0, stream>>>(dstA[rel], deg);
    k_scan1<<<nb, 1024, 0, stream>>>(deg, rowptr[rel], bsum, NN);
    k_scan2<<<1, 64, 0, stream>>>(bsum, nb);
    k_scan3<<<nb3, 1024, 0, stream>>>(rowptr[rel], bsum, cursor, NN, EE);
    k_fill<<<egrid, 256, 0, stream>>>(srcA[rel], dstA[rel], cursor, esrc[rel]);
  }

  k_agg<<<NN, 128, 0, stream>>>(q, kkp, vvp,
                                rowptr[0], esrc[0], rowptr[1], esrc[1],
                                rel_att, rel_msg, rel_pri,
                                h, Wa, ba, skip, out);
}

// Round 3
// 588.025 us; speedup vs baseline: 13.7808x; 1.9476x over previous
//
#include <hip/hip_runtime.h>
#include <hip/hip_bf16.h>

// HGT conv: CSR-gather, per-(node,rel) precomputed kr/vr, 2-way edge-parallel agg.
// ws (floats): kr0[N*128] | vr0[N*128] | kr1[N*128] | vr1[N*128]
// then (ints): rowptr0[50048] rowptr1[50048] esrc0[E] esrc1[E] deg[N] cursor[N] bsum[64]
// q is staged in d_out (block n reads row n before overwriting it).
constexpr int NN  = 50000;
constexpr int EE  = 500000;
constexpr int CF  = 128;
constexpr int NH  = 8;
constexpr int DKC = 16;
constexpr int NPB = 8;    // nodes per block in k_proj

// ---- fused projections + relation transforms: 8 nodes per block --------------
__global__ __launch_bounds__(128)
void k_proj(const float* __restrict__ h,
            const float* __restrict__ Wk, const float* __restrict__ bk,
            const float* __restrict__ Wq, const float* __restrict__ bq,
            const float* __restrict__ Wv, const float* __restrict__ bv,
            const float* __restrict__ rel_att, const float* __restrict__ rel_msg,
            float* __restrict__ q_out,
            float* __restrict__ kr0, float* __restrict__ vr0,
            float* __restrict__ kr1, float* __restrict__ vr1) {
  __shared__ float hs[NPB][CF];
  __shared__ float ks[NPB][CF], vs[NPB][CF];
  const int nb = blockIdx.x * NPB;
  const int t = threadIdx.x;
#pragma unroll
  for (int r = 0; r < NPB; ++r) hs[r][t] = h[(size_t)(nb + r) * CF + t];
  __syncthreads();
  const float bK = bk[t], bQ = bq[t], bV = bv[t];
  float aK[NPB], aQ[NPB], aV[NPB];
#pragma unroll
  for (int r = 0; r < NPB; ++r) { aK[r] = bK; aQ[r] = bQ; aV[r] = bV; }
#pragma unroll 4
  for (int j = 0; j < CF; ++j) {
    const float wk = Wk[j * CF + t], wq = Wq[j * CF + t], wv = Wv[j * CF + t];
#pragma unroll
    for (int r = 0; r < NPB; ++r) {
      const float hv = hs[r][j];
      aK[r] = fmaf(hv, wk, aK[r]);
      aQ[r] = fmaf(hv, wq, aQ[r]);
      aV[r] = fmaf(hv, wv, aV[r]);
    }
  }
#pragma unroll
  for (int r = 0; r < NPB; ++r) {
    q_out[(size_t)(nb + r) * CF + t] = aQ[r];
    ks[r][t] = aK[r];
    vs[r][t] = aV[r];
  }
  __syncthreads();
  const int hh = t >> 4, d = t & 15;
  for (int rel = 0; rel < 2; ++rel) {
    const float* A = rel_att + ((rel * NH + hh) * DKC * DKC) + d;
    const float* M = rel_msg + ((rel * NH + hh) * DKC * DKC) + d;
    float ac[DKC], mc[DKC];
#pragma unroll
    for (int j = 0; j < DKC; ++j) { ac[j] = A[j * DKC]; mc[j] = M[j * DKC]; }
    float* krp = rel ? kr1 : kr0;
    float* vrp = rel ? vr1 : vr0;
#pragma unroll
    for (int r = 0; r < NPB; ++r) {
      float kv = 0.f, vv = 0.f;
#pragma unroll
      for (int j = 0; j < DKC; ++j) {
        kv = fmaf(ks[r][hh * DKC + j], ac[j], kv);
        vv = fmaf(vs[r][hh * DKC + j], mc[j], vv);
      }
      krp[(size_t)(nb + r) * CF + t] = kv;
      vrp[(size_t)(nb + r) * CF + t] = vv;
    }
  }
}

// ---- CSR build ---------------------------------------------------------------
__global__ __launch_bounds__(256)
void k_count(const int* __restrict__ dst, int* __restrict__ deg) {
  const int e = blockIdx.x * 256 + threadIdx.x;
  if (e < EE) atomicAdd(&deg[dst[e]], 1);
}

__global__ __launch_bounds__(1024)
void k_scan1(const int* __restrict__ deg, int* __restrict__ rowptr,
             int* __restrict__ bsum, int n) {
  __shared__ int wsum[16];
  const int i = blockIdx.x * 1024 + threadIdx.x;
  const int lane = threadIdx.x & 63, w = threadIdx.x >> 6;
  const int vdeg = (i < n) ? deg[i] : 0;
  int sc = vdeg;
  for (int off = 1; off < 64; off <<= 1) {
    const int x = __shfl_up(sc, off, 64);
    if (lane >= off) sc += x;
  }
  if (lane == 63) wsum[w] = sc;
  __syncthreads();
  if (threadIdx.x < 16) {
    const int x = wsum[threadIdx.x];
    int s2 = x;
    for (int off = 1; off < 16; off <<= 1) {
      const int y = __shfl_up(s2, off, 64);
      if ((int)threadIdx.x >= off) s2 += y;
    }
    wsum[threadIdx.x] = s2 - x;
    if (threadIdx.x == 15) bsum[blockIdx.x] = s2;
  }
  __syncthreads();
  if (i < n) rowptr[i] = sc - vdeg + wsum[w];
}

__global__ void k_scan2(int* __restrict__ bsum, int nb) {
  const int t = threadIdx.x;
  const int vv = (t < nb) ? bsum[t] : 0;
  int sc = vv;
  for (int off = 1; off < 64; off <<= 1) {
    const int x = __shfl_up(sc, off, 64);
    if (t >= off) sc += x;
  }
  if (t < nb) bsum[t] = sc - vv;
}

__global__ __launch_bounds__(1024)
void k_scan3(int* __restrict__ rowptr, const int* __restrict__ bsum,
             int* __restrict__ cursor, int n, int total) {
  const int i = blockIdx.x * 1024 + threadIdx.x;
  if (i < n) {
    const int vv = rowptr[i] + bsum[blockIdx.x];
    rowptr[i] = vv;
    cursor[i] = vv;
  } else if (i == n) {
    rowptr[n] = total;
  }
}

__global__ __launch_bounds__(256)
void k_fill(const int* __restrict__ src, const int* __restrict__ dst,
            int* __restrict__ cursor, int* __restrict__ esrc) {
  const int e = blockIdx.x * 256 + threadIdx.x;
  if (e < EE) {
    const int pos = atomicAdd(&cursor[dst[e]], 1);
    esrc[pos] = src[e];
  }
}

// ---- fused attention aggregate + GELU + Wa GEMV + skip blend -----------------
// 256 threads per dst node: sub = t>>7 picks even/odd edge substream.
__global__ __launch_bounds__(256)
void k_agg(const float* __restrict__ q,
           const float* __restrict__ kr0, const float* __restrict__ vr0,
           const float* __restrict__ kr1, const float* __restrict__ vr1,
           const int* __restrict__ rowptr0, const int* __restrict__ esrc0,
           const int* __restrict__ rowptr1, const int* __restrict__ esrc1,
           const float* __restrict__ rel_pri,
           const float* __restrict__ h, const float* __restrict__ Wa,
           const float* __restrict__ ba, const float* __restrict__ skip,
           float* __restrict__ out) {
  __shared__ float ts[CF];
  __shared__ float raccs[2][CF], sdens[2][CF];
  const int n = blockIdx.x, t = threadIdx.x;
  const int sub = t >> 7, tt = t & 127;
  const int hh = tt >> 4;
  const float qv = q[(size_t)n * CF + tt];
  float acc = 0.f;

  for (int rel = 0; rel < 2; ++rel) {
    const float* kr = rel ? kr1 : kr0;
    const float* vr = rel ? vr1 : vr0;
    const int* rowptr = rel ? rowptr1 : rowptr0;
    const int* esrc   = rel ? esrc1 : esrc0;
    const float pri = rel_pri[rel * NH + hh] * 0.25f;  // 1/sqrt(16)
    const int e0 = rowptr[n], e1 = rowptr[n + 1];
    float racc = 0.f, sden = 0.f;
    int e = e0 + sub;
    float kvA = 0.f, vvA = 0.f, kvB = 0.f, vvB = 0.f;
    if (e < e1) {
      const int sn = esrc[e];
      kvA = kr[(size_t)sn * CF + tt]; vvA = vr[(size_t)sn * CF + tt];
    }
    if (e + 2 < e1) {
      const int sn = esrc[e + 2];
      kvB = kr[(size_t)sn * CF + tt]; vvB = vr[(size_t)sn * CF + tt];
    }
    for (; e < e1; e += 2) {
      const float kvc = kvA, vvc = vvA;
      kvA = kvB; vvA = vvB;
      if (e + 4 < e1) {
        const int sn = esrc[e + 4];
        kvB = kr[(size_t)sn * CF + tt]; vvB = vr[(size_t)sn * CF + tt];
      }
      float sc = qv * kvc;
      sc += __shfl_xor(sc, 1, 64);
      sc += __shfl_xor(sc, 2, 64);
      sc += __shfl_xor(sc, 4, 64);
      sc += __shfl_xor(sc, 8, 64);
      const float ex = __expf(sc * pri);
      sden += ex;
      racc = fmaf(vvc, ex, racc);
    }
    raccs[sub][tt] = racc;
    sdens[sub][tt] = sden;
    __syncthreads();
    if (sub == 0) {
      const float st = sdens[0][tt] + sdens[1][tt];
      if (st > 0.f) acc += (raccs[0][tt] + raccs[1][tt]) / st;
    }
    __syncthreads();
  }

  if (sub == 0) ts[tt] = 0.5f * acc * (1.f + erff(acc * 0.70710678118f));
  __syncthreads();
  if (sub == 0) {
    float o = ba[tt];
#pragma unroll 8
    for (int j = 0; j < CF; ++j) o = fmaf(ts[j], Wa[j * CF + tt], o);
    const float alpha = 1.f / (1.f + __expf(-skip[0]));
    out[(size_t)n * CF + tt] = o * alpha + h[(size_t)n * CF + tt] * (1.f - alpha);
  }
}

extern "C" void kernel_launch(void* const* d_in, const int* in_sizes, int n_in,
                              void* d_out, int out_size, void* d_ws, size_t ws_size,
                              hipStream_t stream) {
  const float* h = (const float*)d_in[0];
  const int* srcA[2] = {(const int*)d_in[1], (const int*)d_in[3]};
  const int* dstA[2] = {(const int*)d_in[2], (const int*)d_in[4]};
  const float* Wk = (const float*)d_in[5],  *bk = (const float*)d_in[6];
  const float* Wq = (const float*)d_in[7],  *bq = (const float*)d_in[8];
  const float* Wv = (const float*)d_in[9],  *bv = (const float*)d_in[10];
  const float* Wa = (const float*)d_in[11], *ba = (const float*)d_in[12];
  const float* rel_att = (const float*)d_in[13];
  const float* rel_msg = (const float*)d_in[14];
  const float* rel_pri = (const float*)d_in[15];
  const float* skip    = (const float*)d_in[16];
  float* out = (float*)d_out;
  float* q   = (float*)d_out;   // q staged in d_out; k_agg reads row n then overwrites it

  const size_t NC = (size_t)NN * CF;
  float* kr0 = (float*)d_ws;
  float* vr0 = kr0 + NC;
  float* kr1 = vr0 + NC;
  float* vr1 = kr1 + NC;
  int* ip = (int*)(vr1 + NC);
  int* rowptr[2] = {ip, ip + 50048};
  int* esrc[2]   = {ip + 2 * 50048, ip + 2 * 50048 + EE};
  int* deg    = ip + 2 * 50048 + 2 * EE;
  int* cursor = deg + NN;
  int* bsum   = cursor + NN;

  k_proj<<<NN / NPB, 128, 0, stream>>>(h, Wk, bk, Wq, bq, Wv, bv,
                                       rel_att, rel_msg, q, kr0, vr0, kr1, vr1);

  const int egrid = (EE + 255) / 256;
  const int nb = (NN + 1023) / 1024;
  const int nb3 = (NN + 1 + 1023) / 1024;
  for (int rel = 0; rel < 2; ++rel) {
    hipMemsetAsync(deg, 0, NN * sizeof(int), stream);
    k_count<<<egrid, 256, 0, stream>>>(dstA[rel], deg);
    k_scan1<<<nb, 1024, 0, stream>>>(deg, rowptr[rel], bsum, NN);
    k_scan2<<<1, 64, 0, stream>>>(bsum, nb);
    k_scan3<<<nb3, 1024, 0, stream>>>(rowptr[rel], bsum, cursor, NN, EE);
    k_fill<<<egrid, 256, 0, stream>>>(srcA[rel], dstA[rel], cursor, esrc[rel]);
  }

  k_agg<<<NN, 256, 0, stream>>>(q, kr0, vr0, kr1, vr1,
                                rowptr[0], esrc[0], rowptr[1], esrc[1],
                                rel_pri, h, Wa, ba, skip, out);
}

// Round 4
// 447.688 us; speedup vs baseline: 18.1007x; 1.3135x over previous
//
#include <hip/hip_runtime.h>
#include <hip/hip_bf16.h>

// HGT conv v4: bf16 kr/vr gathers, 4-way wave-parallel attention, split MLP,
// single-pass CSR for both relations.
// ws: q[N*128]f32 | t_agg[N*128]f32 | kr0,vr0,kr1,vr1 [N*128]bf16
//     | rowptrC[2N+2] esrcC[2E] deg2[2N] cursor[2N] bsum[128] (ints)
constexpr int NN  = 50000;
constexpr int EE  = 500000;
constexpr int CF  = 128;
constexpr int NH  = 8;
constexpr int DKC = 16;
constexpr int NPB = 8;

typedef unsigned int uint32;
typedef unsigned short ushort16;

__device__ __forceinline__ float bf16lo(uint32 u) { return __uint_as_float(u << 16); }
__device__ __forceinline__ float bf16hi(uint32 u) { return __uint_as_float(u & 0xffff0000u); }

// ---- projections + relation transforms: 8 nodes/block ------------------------
__global__ __launch_bounds__(128)
void k_proj(const float* __restrict__ h,
            const float* __restrict__ Wk, const float* __restrict__ bk,
            const float* __restrict__ Wq, const float* __restrict__ bq,
            const float* __restrict__ Wv, const float* __restrict__ bv,
            const float* __restrict__ rel_att, const float* __restrict__ rel_msg,
            float* __restrict__ q_out,
            __hip_bfloat16* __restrict__ kr0, __hip_bfloat16* __restrict__ vr0,
            __hip_bfloat16* __restrict__ kr1, __hip_bfloat16* __restrict__ vr1) {
  __shared__ float hs[NPB][CF];
  __shared__ float ks[NPB][CF], vs[NPB][CF];
  const int nb = blockIdx.x * NPB;
  const int t = threadIdx.x;
#pragma unroll
  for (int r = 0; r < NPB; ++r) hs[r][t] = h[(size_t)(nb + r) * CF + t];
  __syncthreads();
  const float bK = bk[t], bQ = bq[t], bV = bv[t];
  float aK[NPB], aQ[NPB], aV[NPB];
#pragma unroll
  for (int r = 0; r < NPB; ++r) { aK[r] = bK; aQ[r] = bQ; aV[r] = bV; }
#pragma unroll 4
  for (int j = 0; j < CF; ++j) {
    const float wk = Wk[j * CF + t], wq = Wq[j * CF + t], wv = Wv[j * CF + t];
#pragma unroll
    for (int r = 0; r < NPB; ++r) {
      const float hv = hs[r][j];
      aK[r] = fmaf(hv, wk, aK[r]);
      aQ[r] = fmaf(hv, wq, aQ[r]);
      aV[r] = fmaf(hv, wv, aV[r]);
    }
  }
#pragma unroll
  for (int r = 0; r < NPB; ++r) {
    q_out[(size_t)(nb + r) * CF + t] = aQ[r];
    ks[r][t] = aK[r];
    vs[r][t] = aV[r];
  }
  __syncthreads();
  const int hh = t >> 4, d = t & 15;
  for (int rel = 0; rel < 2; ++rel) {
    const float* A = rel_att + ((rel * NH + hh) * DKC * DKC) + d;
    const float* M = rel_msg + ((rel * NH + hh) * DKC * DKC) + d;
    float ac[DKC], mc[DKC];
#pragma unroll
    for (int j = 0; j < DKC; ++j) { ac[j] = A[j * DKC]; mc[j] = M[j * DKC]; }
    __hip_bfloat16* krp = rel ? kr1 : kr0;
    __hip_bfloat16* vrp = rel ? vr1 : vr0;
#pragma unroll
    for (int r = 0; r < NPB; ++r) {
      float kv = 0.f, vv = 0.f;
#pragma unroll
      for (int j = 0; j < DKC; ++j) {
        kv = fmaf(ks[r][hh * DKC + j], ac[j], kv);
        vv = fmaf(vs[r][hh * DKC + j], mc[j], vv);
      }
      krp[(size_t)(nb + r) * CF + t] = __float2bfloat16(kv);
      vrp[(size_t)(nb + r) * CF + t] = __float2bfloat16(vv);
    }
  }
}

// ---- CSR build (both relations in one concatenated index space) --------------
__global__ __launch_bounds__(256)
void k_count2(const int* __restrict__ dst0, const int* __restrict__ dst1,
              int* __restrict__ deg2) {
  const int e = blockIdx.x * 256 + threadIdx.x;
  if (e < EE) atomicAdd(&deg2[dst0[e]], 1);
  else if (e < 2 * EE) atomicAdd(&deg2[NN + dst1[e - EE]], 1);
}

__global__ __launch_bounds__(1024)
void k_scan1(const int* __restrict__ deg, int* __restrict__ rowptr,
             int* __restrict__ bsum, int n) {
  __shared__ int wsum[16];
  const int i = blockIdx.x * 1024 + threadIdx.x;
  const int lane = threadIdx.x & 63, w = threadIdx.x >> 6;
  const int vdeg = (i < n) ? deg[i] : 0;
  int sc = vdeg;
  for (int off = 1; off < 64; off <<= 1) {
    const int x = __shfl_up(sc, off, 64);
    if (lane >= off) sc += x;
  }
  if (lane == 63) wsum[w] = sc;
  __syncthreads();
  if (threadIdx.x < 16) {
    const int x = wsum[threadIdx.x];
    int s2 = x;
    for (int off = 1; off < 16; off <<= 1) {
      const int y = __shfl_up(s2, off, 64);
      if ((int)threadIdx.x >= off) s2 += y;
    }
    wsum[threadIdx.x] = s2 - x;
    if (threadIdx.x == 15) bsum[blockIdx.x] = s2;
  }
  __syncthreads();
  if (i < n) rowptr[i] = sc - vdeg + wsum[w];
}

__global__ __launch_bounds__(128)
void k_scan2(int* __restrict__ bsum, int nb) {  // nb <= 128
  __shared__ int tmp[128];
  const int t = threadIdx.x;
  const int v = (t < nb) ? bsum[t] : 0;
  tmp[t] = v;
  __syncthreads();
  for (int off = 1; off < 128; off <<= 1) {
    const int x = (t >= off) ? tmp[t - off] : 0;
    __syncthreads();
    tmp[t] += x;
    __syncthreads();
  }
  if (t < nb) bsum[t] = tmp[t] - v;  // exclusive
}

__global__ __launch_bounds__(1024)
void k_scan3(int* __restrict__ rowptr, const int* __restrict__ bsum,
             int* __restrict__ cursor, int n, int total) {
  const int i = blockIdx.x * 1024 + threadIdx.x;
  if (i < n) {
    const int vv = rowptr[i] + bsum[blockIdx.x];
    rowptr[i] = vv;
    cursor[i] = vv;
  } else if (i == n) {
    rowptr[n] = total;
  }
}

__global__ __launch_bounds__(256)
void k_fill2(const int* __restrict__ src0, const int* __restrict__ dst0,
             const int* __restrict__ src1, const int* __restrict__ dst1,
             int* __restrict__ cursor, int* __restrict__ esrc) {
  const int e = blockIdx.x * 256 + threadIdx.x;
  if (e < EE) {
    const int pos = atomicAdd(&cursor[dst0[e]], 1);
    esrc[pos] = src0[e];
  } else if (e < 2 * EE) {
    const int pos = atomicAdd(&cursor[NN + dst1[e - EE]], 1);
    esrc[pos] = src1[e - EE];
  }
}

// ---- attention aggregate: 1 node/block, 4 waves, each wave all 8 heads -------
// Lane l handles row elements 2l, 2l+1 (head hh = l>>3).
__global__ __launch_bounds__(256)
void k_att(const float* __restrict__ q,
           const __hip_bfloat16* __restrict__ kr0, const __hip_bfloat16* __restrict__ vr0,
           const __hip_bfloat16* __restrict__ kr1, const __hip_bfloat16* __restrict__ vr1,
           const int* __restrict__ rowptrC, const int* __restrict__ esrcC,
           const float* __restrict__ rel_pri, float* __restrict__ t_agg) {
  __shared__ float2 raccS[4][64];
  __shared__ float sdenS[4][64];
  const int n = blockIdx.x, t = threadIdx.x;
  const int w = t >> 6, l = t & 63;
  const int hh = l >> 3;
  const float2 qv = *(const float2*)(q + (size_t)n * CF + 2 * l);
  float accx = 0.f, accy = 0.f;

  for (int rel = 0; rel < 2; ++rel) {
    const ushort16* kr = (const ushort16*)(rel ? kr1 : kr0);
    const ushort16* vr = (const ushort16*)(rel ? vr1 : vr0);
    const int base = rel ? NN + n : n;
    const int e0 = rowptrC[base], e1 = rowptrC[base + 1];
    const float pri = rel_pri[rel * NH + hh] * 0.25f;  // 1/sqrt(16)
    float raccx = 0.f, raccy = 0.f, sden = 0.f;
    int e = e0 + w;
    uint32 kA = 0, vA = 0, kB = 0, vB = 0;
    if (e < e1) {
      const int sn = esrcC[e];
      kA = *(const uint32*)(kr + (size_t)sn * CF + 2 * l);
      vA = *(const uint32*)(vr + (size_t)sn * CF + 2 * l);
    }
    if (e + 4 < e1) {
      const int sn = esrcC[e + 4];
      kB = *(const uint32*)(kr + (size_t)sn * CF + 2 * l);
      vB = *(const uint32*)(vr + (size_t)sn * CF + 2 * l);
    }
    for (; e < e1; e += 4) {
      const uint32 kc = kA, vc = vA;
      kA = kB; vA = vB;
      if (e + 8 < e1) {
        const int sn = esrcC[e + 8];
        kB = *(const uint32*)(kr + (size_t)sn * CF + 2 * l);
        vB = *(const uint32*)(vr + (size_t)sn * CF + 2 * l);
      }
      float sc = fmaf(qv.x, bf16lo(kc), qv.y * bf16hi(kc));
      sc += __shfl_xor(sc, 1, 64);
      sc += __shfl_xor(sc, 2, 64);
      sc += __shfl_xor(sc, 4, 64);
      const float ex = __expf(sc * pri);
      sden += ex;
      raccx = fmaf(bf16lo(vc), ex, raccx);
      raccy = fmaf(bf16hi(vc), ex, raccy);
    }
    raccS[w][l] = make_float2(raccx, raccy);
    sdenS[w][l] = sden;
    __syncthreads();
    const float st = sdenS[0][l] + sdenS[1][l] + sdenS[2][l] + sdenS[3][l];
    if (st > 0.f) {
      const float2 r0 = raccS[0][l], r1 = raccS[1][l], r2 = raccS[2][l], r3 = raccS[3][l];
      accx += (r0.x + r1.x + r2.x + r3.x) / st;
      accy += (r0.y + r1.y + r2.y + r3.y) / st;
    }
    __syncthreads();
  }
  if (w == 0) {
    t_agg[(size_t)n * CF + 2 * l] = accx;
    t_agg[(size_t)n * CF + 2 * l + 1] = accy;
  }
}

// ---- GELU + Wa GEMV + skip blend: 8 nodes/block ------------------------------
__global__ __launch_bounds__(128)
void k_mlp(const float* __restrict__ t_agg, const float* __restrict__ h,
           const float* __restrict__ Wa, const float* __restrict__ ba,
           const float* __restrict__ skip, float* __restrict__ out) {
  __shared__ float ts[NPB][CF];
  const int nb = blockIdx.x * NPB;
  const int t = threadIdx.x;
#pragma unroll
  for (int r = 0; r < NPB; ++r) {
    const float x = t_agg[(size_t)(nb + r) * CF + t];
    ts[r][t] = 0.5f * x * (1.f + erff(x * 0.70710678118f));
  }
  __syncthreads();
  float o[NPB];
  const float b0 = ba[t];
#pragma unroll
  for (int r = 0; r < NPB; ++r) o[r] = b0;
#pragma unroll 4
  for (int j = 0; j < CF; ++j) {
    const float wa = Wa[j * CF + t];
#pragma unroll
    for (int r = 0; r < NPB; ++r) o[r] = fmaf(ts[r][j], wa, o[r]);
  }
  const float alpha = 1.f / (1.f + __expf(-skip[0]));
#pragma unroll
  for (int r = 0; r < NPB; ++r)
    out[(size_t)(nb + r) * CF + t] = o[r] * alpha + h[(size_t)(nb + r) * CF + t] * (1.f - alpha);
}

extern "C" void kernel_launch(void* const* d_in, const int* in_sizes, int n_in,
                              void* d_out, int out_size, void* d_ws, size_t ws_size,
                              hipStream_t stream) {
  const float* h = (const float*)d_in[0];
  const int* src0 = (const int*)d_in[1];
  const int* dst0 = (const int*)d_in[2];
  const int* src1 = (const int*)d_in[3];
  const int* dst1 = (const int*)d_in[4];
  const float* Wk = (const float*)d_in[5],  *bk = (const float*)d_in[6];
  const float* Wq = (const float*)d_in[7],  *bq = (const float*)d_in[8];
  const float* Wv = (const float*)d_in[9],  *bv = (const float*)d_in[10];
  const float* Wa = (const float*)d_in[11], *ba = (const float*)d_in[12];
  const float* rel_att = (const float*)d_in[13];
  const float* rel_msg = (const float*)d_in[14];
  const float* rel_pri = (const float*)d_in[15];
  const float* skip    = (const float*)d_in[16];
  float* out = (float*)d_out;

  const size_t NC = (size_t)NN * CF;
  float* q     = (float*)d_ws;
  float* t_agg = q + NC;
  __hip_bfloat16* kr0 = (__hip_bfloat16*)(t_agg + NC);
  __hip_bfloat16* vr0 = kr0 + NC;
  __hip_bfloat16* kr1 = vr0 + NC;
  __hip_bfloat16* vr1 = kr1 + NC;
  int* ip = (int*)(vr1 + NC);
  int* rowptrC = ip;                       // 2N+2
  int* esrcC   = rowptrC + 2 * NN + 2;     // 2E
  int* deg2    = esrcC + 2 * EE;           // 2N
  int* cursor  = deg2 + 2 * NN;            // 2N
  int* bsum    = cursor + 2 * NN;          // 128

  k_proj<<<NN / NPB, 128, 0, stream>>>(h, Wk, bk, Wq, bq, Wv, bv,
                                       rel_att, rel_msg, q, kr0, vr0, kr1, vr1);

  const int egrid2 = (2 * EE + 255) / 256;
  const int n2 = 2 * NN;
  const int nb = (n2 + 1023) / 1024;        // 98
  const int nb3 = (n2 + 1 + 1023) / 1024;
  hipMemsetAsync(deg2, 0, n2 * sizeof(int), stream);
  k_count2<<<egrid2, 256, 0, stream>>>(dst0, dst1, deg2);
  k_scan1<<<nb, 1024, 0, stream>>>(deg2, rowptrC, bsum, n2);
  k_scan2<<<1, 128, 0, stream>>>(bsum, nb);
  k_scan3<<<nb3, 1024, 0, stream>>>(rowptrC, bsum, cursor, n2, 2 * EE);
  k_fill2<<<egrid2, 256, 0, stream>>>(src0, dst0, src1, dst1, cursor, esrcC);

  k_att<<<NN, 256, 0, stream>>>(q, kr0, vr0, kr1, vr1, rowptrC, esrcC,
                                rel_pri, t_agg);
  k_mlp<<<NN / NPB, 128, 0, stream>>>(t_agg, h, Wa, ba, skip, out);
}

// Round 6
// 410.395 us; speedup vs baseline: 19.7455x; 1.0909x over previous
//
#include <hip/hip_runtime.h>
#include <hip/hip_bf16.h>

// HGT conv v5: MFMA bf16 projections + MLP, bf16 gathers, CSR attention.
// ws: q[N*128]f32 | t_agg[N*128]f32 | kr0,vr0,kr1,vr1[N*128]bf16(short)
//     | wfragF[4*24*64*8]short | wfragA[4*8*64*8]short | ints(CSR)
constexpr int NN  = 50000;
constexpr int EE  = 500000;
constexpr int CF  = 128;
constexpr int NH  = 8;
constexpr int BM  = 64;    // GEMM row tile (nodes)

typedef unsigned int uint32;
typedef __attribute__((ext_vector_type(8))) short short8v;  // 8 bf16 (4 VGPRs)
typedef __attribute__((ext_vector_type(4))) float f32x4;

__device__ __forceinline__ float bf16lo(uint32 u) { return __uint_as_float(u << 16); }
__device__ __forceinline__ float bf16hi(uint32 u) { return __uint_as_float(u & 0xffff0000u); }
__device__ __forceinline__ short f2bf(float f) {   // RNE f32->bf16
  unsigned u = __float_as_uint(f);
  return (short)((u + 0x7fffu + ((u >> 16) & 1u)) >> 16);
}
__device__ __forceinline__ float bf2f(short s) {
  return __uint_as_float(((unsigned)(unsigned short)s) << 16);
}

// ---- pack W (f32, [128][*]) into MFMA B-fragment order -----------------------
// frag[((kt*nct+ct)*64+l)*8+i] = bf16( W[kt*32+(l>>4)*8+i][ct*16+(l&15)] )
__global__ __launch_bounds__(64)
void k_wprep(const float* __restrict__ W0, const float* __restrict__ W1,
             const float* __restrict__ W2, short* __restrict__ frag, int nct) {
  const int b = blockIdx.x;            // kt*nct + ct
  const int ct = b % nct;
  const int l = threadIdx.x;
  const int c = ct * 16 + (l & 15);
  const float* W; int lc;
  if (nct == 8) { W = W0; lc = c; }
  else {
    const int m = c >> 7; lc = c & 127;
    W = (m == 0) ? W0 : ((m == 1) ? W1 : W2);
  }
  short* dst = frag + ((size_t)b * 64 + l) * 8;
  const int k0 = (b / nct) * 32 + (l >> 4) * 8;
#pragma unroll
  for (int i = 0; i < 8; ++i) dst[i] = f2bf(W[(k0 + i) * CF + lc]);
}

// ---- MFMA projection: KQV GEMM + bias + per-head relation transforms ---------
// 64 nodes/block, 256 threads (4 waves), wave w -> col-tiles w*6..w*6+5 of 24.
// cols 0-127 = K, 128-255 = Q, 256-383 = V.
__global__ __launch_bounds__(256)
void k_projm(const float* __restrict__ h, const short* __restrict__ wfrag,
             const float* __restrict__ bk, const float* __restrict__ bq,
             const float* __restrict__ bv,
             const float* __restrict__ rel_att, const float* __restrict__ rel_msg,
             float* __restrict__ q_out,
             short* __restrict__ kr0, short* __restrict__ vr0,
             short* __restrict__ kr1, short* __restrict__ vr1) {
  __shared__ __align__(16) short ldsA[BM * 136];  // h tile bf16; reused as K stage
  __shared__ __align__(16) short ldsV[BM * 136];
  const int n0 = blockIdx.x * BM;
  const int t = threadIdx.x;
  const int w = t >> 6, l = t & 63;

  // stage h tile (f32 -> bf16, padded stride 136)
  for (int idx = t; idx < BM * 32; idx += 256) {
    const int r = idx >> 5, c4 = idx & 31;
    float4 hv = make_float4(0.f, 0.f, 0.f, 0.f);
    if (n0 + r < NN) hv = *(const float4*)(h + (size_t)(n0 + r) * CF + c4 * 4);
    short* d = ldsA + r * 136 + c4 * 4;
    d[0] = f2bf(hv.x); d[1] = f2bf(hv.y); d[2] = f2bf(hv.z); d[3] = f2bf(hv.w);
  }
  __syncthreads();

  f32x4 acc[4][6] = {};
#pragma unroll
  for (int kt = 0; kt < 4; ++kt) {
    const int ko = kt * 32 + (l >> 4) * 8;
    short8v af[4];
#pragma unroll
    for (int rt = 0; rt < 4; ++rt)
      af[rt] = *(const short8v*)(ldsA + (rt * 16 + (l & 15)) * 136 + ko);
#pragma unroll
    for (int cti = 0; cti < 6; ++cti) {
      const int ct = w * 6 + cti;
      const short8v bf = *(const short8v*)(wfrag + (((size_t)(kt * 24 + ct)) * 64 + l) * 8);
#pragma unroll
      for (int rt = 0; rt < 4; ++rt)
        acc[rt][cti] = __builtin_amdgcn_mfma_f32_16x16x32_bf16(af[rt], bf, acc[rt][cti], 0, 0, 0);
    }
  }
  __syncthreads();  // ldsA free now

  // epilogue: bias; Q -> global f32, K/V -> LDS bf16
  const int cl = l & 15, rg = (l >> 4) * 4;
#pragma unroll
  for (int cti = 0; cti < 6; ++cti) {
    const int ct = w * 6 + cti;
    const int c = ct * 16 + cl;
    const int m = c >> 7, lc = c & 127;
    const float bias = (m == 0) ? bk[lc] : ((m == 1) ? bq[lc] : bv[lc]);
#pragma unroll
    for (int rt = 0; rt < 4; ++rt) {
#pragma unroll
      for (int r = 0; r < 4; ++r) {
        const int row = rt * 16 + rg + r;
        const float v = acc[rt][cti][r] + bias;
        if (m == 1) {
          if (n0 + row < NN) q_out[(size_t)(n0 + row) * CF + lc] = v;
        } else if (m == 0) {
          ldsA[row * 136 + lc] = f2bf(v);
        } else {
          ldsV[row * 136 + lc] = f2bf(v);
        }
      }
    }
  }
  __syncthreads();

  // per-head 16x16 relation transforms: kr = K*att, vr = V*msg
  const int tt = t & 127, half = t >> 7;
  const int hh = tt >> 4, d = tt & 15;
  for (int rel = 0; rel < 2; ++rel) {
    const float* A = rel_att + ((rel * NH + hh) * 256) + d;
    const float* M = rel_msg + ((rel * NH + hh) * 256) + d;
    float ac[16], mc[16];
#pragma unroll
    for (int j = 0; j < 16; ++j) { ac[j] = A[j * 16]; mc[j] = M[j * 16]; }
    short* krp = rel ? kr1 : kr0;
    short* vrp = rel ? vr1 : vr0;
    for (int r = half; r < BM; r += 2) {
      if (n0 + r >= NN) break;
      float kv = 0.f, vv = 0.f;
#pragma unroll
      for (int j = 0; j < 16; ++j) {
        kv = fmaf(bf2f(ldsA[r * 136 + hh * 16 + j]), ac[j], kv);
        vv = fmaf(bf2f(ldsV[r * 136 + hh * 16 + j]), mc[j], vv);
      }
      krp[(size_t)(n0 + r) * CF + tt] = f2bf(kv);
      vrp[(size_t)(n0 + r) * CF + tt] = f2bf(vv);
    }
  }
}

// ---- CSR build (both relations, concatenated index space) --------------------
__global__ __launch_bounds__(256)
void k_count2(const int* __restrict__ dst0, const int* __restrict__ dst1,
              int* __restrict__ deg2) {
  const int e = blockIdx.x * 256 + threadIdx.x;
  if (e < EE) atomicAdd(&deg2[dst0[e]], 1);
  else if (e < 2 * EE) atomicAdd(&deg2[NN + dst1[e - EE]], 1);
}

__global__ __launch_bounds__(1024)
void k_scan1(const int* __restrict__ deg, int* __restrict__ rowptr,
             int* __restrict__ bsum, int n) {
  __shared__ int wsum[16];
  const int i = blockIdx.x * 1024 + threadIdx.x;
  const int lane = threadIdx.x & 63, w = threadIdx.x >> 6;
  const int vdeg = (i < n) ? deg[i] : 0;
  int sc = vdeg;
  for (int off = 1; off < 64; off <<= 1) {
    const int x = __shfl_up(sc, off, 64);
    if (lane >= off) sc += x;
  }
  if (lane == 63) wsum[w] = sc;
  __syncthreads();
  if (threadIdx.x < 16) {
    const int x = wsum[threadIdx.x];
    int s2 = x;
    for (int off = 1; off < 16; off <<= 1) {
      const int y = __shfl_up(s2, off, 64);
      if ((int)threadIdx.x >= off) s2 += y;
    }
    wsum[threadIdx.x] = s2 - x;
    if (threadIdx.x == 15) bsum[blockIdx.x] = s2;
  }
  __syncthreads();
  if (i < n) rowptr[i] = sc - vdeg + wsum[w];
}

__global__ __launch_bounds__(128)
void k_scan2(int* __restrict__ bsum, int nb) {
  __shared__ int tmp[128];
  const int t = threadIdx.x;
  const int v = (t < nb) ? bsum[t] : 0;
  tmp[t] = v;
  __syncthreads();
  for (int off = 1; off < 128; off <<= 1) {
    const int x = (t >= off) ? tmp[t - off] : 0;
    __syncthreads();
    tmp[t] += x;
    __syncthreads();
  }
  if (t < nb) bsum[t] = tmp[t] - v;
}

__global__ __launch_bounds__(1024)
void k_scan3(int* __restrict__ rowptr, const int* __restrict__ bsum,
             int* __restrict__ cursor, int n, int total) {
  const int i = blockIdx.x * 1024 + threadIdx.x;
  if (i < n) {
    const int vv = rowptr[i] + bsum[blockIdx.x];
    rowptr[i] = vv;
    cursor[i] = vv;
  } else if (i == n) {
    rowptr[n] = total;
  }
}

__global__ __launch_bounds__(256)
void k_fill2(const int* __restrict__ src0, const int* __restrict__ dst0,
             const int* __restrict__ src1, const int* __restrict__ dst1,
             int* __restrict__ cursor, int* __restrict__ esrc) {
  const int e = blockIdx.x * 256 + threadIdx.x;
  if (e < EE) {
    const int pos = atomicAdd(&cursor[dst0[e]], 1);
    esrc[pos] = src0[e];
  } else if (e < 2 * EE) {
    const int pos = atomicAdd(&cursor[NN + dst1[e - EE]], 1);
    esrc[pos] = src1[e - EE];
  }
}

// ---- attention aggregate: 1 node/block, 4 waves, each wave all 8 heads -------
__global__ __launch_bounds__(256)
void k_att(const float* __restrict__ q,
           const short* __restrict__ kr0, const short* __restrict__ vr0,
           const short* __restrict__ kr1, const short* __restrict__ vr1,
           const int* __restrict__ rowptrC, const int* __restrict__ esrcC,
           const float* __restrict__ rel_pri, float* __restrict__ t_agg) {
  __shared__ float2 raccS[4][64];
  __shared__ float sdenS[4][64];
  const int n = blockIdx.x, t = threadIdx.x;
  const int w = t >> 6, l = t & 63;
  const int hh = l >> 3;
  const float2 qv = *(const float2*)(q + (size_t)n * CF + 2 * l);
  float accx = 0.f, accy = 0.f;

  for (int rel = 0; rel < 2; ++rel) {
    const unsigned short* kr = (const unsigned short*)(rel ? kr1 : kr0);
    const unsigned short* vr = (const unsigned short*)(rel ? vr1 : vr0);
    const int base = rel ? NN + n : n;
    const int e0 = rowptrC[base], e1 = rowptrC[base + 1];
    const float pri = rel_pri[rel * NH + hh] * 0.25f;
    float raccx = 0.f, raccy = 0.f, sden = 0.f;
    int e = e0 + w;
    uint32 kA = 0, vA = 0, kB = 0, vB = 0;
    if (e < e1) {
      const int sn = esrcC[e];
      kA = *(const uint32*)(kr + (size_t)sn * CF + 2 * l);
      vA = *(const uint32*)(vr + (size_t)sn * CF + 2 * l);
    }
    if (e + 4 < e1) {
      const int sn = esrcC[e + 4];
      kB = *(const uint32*)(kr + (size_t)sn * CF + 2 * l);
      vB = *(const uint32*)(vr + (size_t)sn * CF + 2 * l);
    }
    for (; e < e1; e += 4) {
      const uint32 kc = kA, vc = vA;
      kA = kB; vA = vB;
      if (e + 8 < e1) {
        const int sn = esrcC[e + 8];
        kB = *(const uint32*)(kr + (size_t)sn * CF + 2 * l);
        vB = *(const uint32*)(vr + (size_t)sn * CF + 2 * l);
      }
      float sc = fmaf(qv.x, bf16lo(kc), qv.y * bf16hi(kc));
      sc += __shfl_xor(sc, 1, 64);
      sc += __shfl_xor(sc, 2, 64);
      sc += __shfl_xor(sc, 4, 64);
      const float ex = __expf(sc * pri);
      sden += ex;
      raccx = fmaf(bf16lo(vc), ex, raccx);
      raccy = fmaf(bf16hi(vc), ex, raccy);
    }
    raccS[w][l] = make_float2(raccx, raccy);
    sdenS[w][l] = sden;
    __syncthreads();
    const float st = sdenS[0][l] + sdenS[1][l] + sdenS[2][l] + sdenS[3][l];
    if (st > 0.f) {
      const float2 r0 = raccS[0][l], r1 = raccS[1][l], r2 = raccS[2][l], r3 = raccS[3][l];
      accx += (r0.x + r1.x + r2.x + r3.x) / st;
      accy += (r0.y + r1.y + r2.y + r3.y) / st;
    }
    __syncthreads();
  }
  if (w == 0) {
    t_agg[(size_t)n * CF + 2 * l] = accx;
    t_agg[(size_t)n * CF + 2 * l + 1] = accy;
  }
}

// ---- MFMA MLP: GELU(t_agg) @ Wa + ba, skip blend ------------------------------
__global__ __launch_bounds__(256)
void k_mlpm(const float* __restrict__ t_agg, const float* __restrict__ h,
            const short* __restrict__ wafrag, const float* __restrict__ ba,
            const float* __restrict__ skip, float* __restrict__ out) {
  __shared__ __align__(16) short ldsA[BM * 136];
  const int n0 = blockIdx.x * BM;
  const int t = threadIdx.x;
  const int w = t >> 6, l = t & 63;

  for (int idx = t; idx < BM * 32; idx += 256) {
    const int r = idx >> 5, c4 = idx & 31;
    float4 x = make_float4(0.f, 0.f, 0.f, 0.f);
    if (n0 + r < NN) x = *(const float4*)(t_agg + (size_t)(n0 + r) * CF + c4 * 4);
    short* d = ldsA + r * 136 + c4 * 4;
    d[0] = f2bf(0.5f * x.x * (1.f + erff(x.x * 0.70710678118f)));
    d[1] = f2bf(0.5f * x.y * (1.f + erff(x.y * 0.70710678118f)));
    d[2] = f2bf(0.5f * x.z * (1.f + erff(x.z * 0.70710678118f)));
    d[3] = f2bf(0.5f * x.w * (1.f + erff(x.w * 0.70710678118f)));
  }
  __syncthreads();

  f32x4 acc[4][2] = {};
#pragma unroll
  for (int kt = 0; kt < 4; ++kt) {
    const int ko = kt * 32 + (l >> 4) * 8;
    short8v af[4];
#pragma unroll
    for (int rt = 0; rt < 4; ++rt)
      af[rt] = *(const short8v*)(ldsA + (rt * 16 + (l & 15)) * 136 + ko);
#pragma unroll
    for (int cti = 0; cti < 2; ++cti) {
      const int ct = w * 2 + cti;
      const short8v bf = *(const short8v*)(wafrag + (((size_t)(kt * 8 + ct)) * 64 + l) * 8);
#pragma unroll
      for (int rt = 0; rt < 4; ++rt)
        acc[rt][cti] = __builtin_amdgcn_mfma_f32_16x16x32_bf16(af[rt], bf, acc[rt][cti], 0, 0, 0);
    }
  }

  const float alpha = 1.f / (1.f + __expf(-skip[0]));
  const int cl = l & 15, rg = (l >> 4) * 4;
#pragma unroll
  for (int cti = 0; cti < 2; ++cti) {
    const int c = (w * 2 + cti) * 16 + cl;
    const float bias = ba[c];
#pragma unroll
    for (int rt = 0; rt < 4; ++rt) {
#pragma unroll
      for (int r = 0; r < 4; ++r) {
        const int row = rt * 16 + rg + r;
        if (n0 + row < NN)
          out[(size_t)(n0 + row) * CF + c] =
              (acc[rt][cti][r] + bias) * alpha + h[(size_t)(n0 + row) * CF + c] * (1.f - alpha);
      }
    }
  }
}

extern "C" void kernel_launch(void* const* d_in, const int* in_sizes, int n_in,
                              void* d_out, int out_size, void* d_ws, size_t ws_size,
                              hipStream_t stream) {
  const float* h = (const float*)d_in[0];
  const int* src0 = (const int*)d_in[1];
  const int* dst0 = (const int*)d_in[2];
  const int* src1 = (const int*)d_in[3];
  const int* dst1 = (const int*)d_in[4];
  const float* Wk = (const float*)d_in[5],  *bk = (const float*)d_in[6];
  const float* Wq = (const float*)d_in[7],  *bq = (const float*)d_in[8];
  const float* Wv = (const float*)d_in[9],  *bv = (const float*)d_in[10];
  const float* Wa = (const float*)d_in[11], *ba = (const float*)d_in[12];
  const float* rel_att = (const float*)d_in[13];
  const float* rel_msg = (const float*)d_in[14];
  const float* rel_pri = (const float*)d_in[15];
  const float* skip    = (const float*)d_in[16];
  float* out = (float*)d_out;

  const size_t NC = (size_t)NN * CF;
  float* q     = (float*)d_ws;
  float* t_agg = q + NC;
  short* kr0 = (short*)(t_agg + NC);
  short* vr0 = kr0 + NC;
  short* kr1 = vr0 + NC;
  short* vr1 = kr1 + NC;
  short* wfragF = vr1 + NC;                 // 4*24*64*8 = 49152
  short* wfragA = wfragF + 4 * 24 * 64 * 8; // 4*8*64*8 = 16384
  int* ip = (int*)(wfragA + 4 * 8 * 64 * 8);
  int* rowptrC = ip;
  int* esrcC   = rowptrC + 2 * NN + 2;
  int* deg2    = esrcC + 2 * EE;
  int* cursor  = deg2 + 2 * NN;
  int* bsum    = cursor + 2 * NN;

  k_wprep<<<96, 64, 0, stream>>>(Wk, Wq, Wv, wfragF, 24);
  k_wprep<<<32, 64, 0, stream>>>(Wa, Wa, Wa, wfragA, 8);

  const int mgrid = (NN + BM - 1) / BM;  // 782
  k_projm<<<mgrid, 256, 0, stream>>>(h, wfragF, bk, bq, bv, rel_att, rel_msg,
                                     q, kr0, vr0, kr1, vr1);

  const int egrid2 = (2 * EE + 255) / 256;
  const int n2 = 2 * NN;
  const int nb = (n2 + 1023) / 1024;
  const int nb3 = (n2 + 1 + 1023) / 1024;
  hipMemsetAsync(deg2, 0, n2 * sizeof(int), stream);
  k_count2<<<egrid2, 256, 0, stream>>>(dst0, dst1, deg2);
  k_scan1<<<nb, 1024, 0, stream>>>(deg2, rowptrC, bsum, n2);
  k_scan2<<<1, 128, 0, stream>>>(bsum, nb);
  k_scan3<<<nb3, 1024, 0, stream>>>(rowptrC, bsum, cursor, n2, 2 * EE);
  k_fill2<<<egrid2, 256, 0, stream>>>(src0, dst0, src1, dst1, cursor, esrcC);

  k_att<<<NN, 256, 0, stream>>>(q, kr0, vr0, kr1, vr1, rowptrC, esrcC,
                                rel_pri, t_agg);
  k_mlpm<<<mgrid, 256, 0, stream>>>(t_agg, h, wfragA, ba, skip, out);
}

// Round 7
// 291.123 us; speedup vs baseline: 27.8351x; 1.4097x over previous
//
#include <hip/hip_runtime.h>
#include <hip/hip_bf16.h>

// HGT conv v6: folded relation transforms (Wk@blockdiag(att) precomputed),
// single 640-col MFMA projection, packed krv gathers (uint4/edge/lane), CSR attention.
// ws: q[N*128]f32 | t_agg[N*128]f32 | brel[512]f32 | krv0,krv1[N*32]uint4
//     | wfragBig[4*40*64*8]short | wfragA[4*8*64*8]short | ints(CSR)
constexpr int NN  = 50000;
constexpr int EE  = 500000;
constexpr int CF  = 128;
constexpr int NH  = 8;
constexpr int BM  = 64;

typedef unsigned int uint32;
typedef __attribute__((ext_vector_type(8))) short short8v;
typedef __attribute__((ext_vector_type(4))) float f32x4;

__device__ __forceinline__ float bf16lo(uint32 u) { return __uint_as_float(u << 16); }
__device__ __forceinline__ float bf16hi(uint32 u) { return __uint_as_float(u & 0xffff0000u); }
__device__ __forceinline__ short f2bf(float f) {
  unsigned u = __float_as_uint(f);
  return (short)((u + 0x7fffu + ((u >> 16) & 1u)) >> 16);
}

// ---- pack W (f32 [128][cols]) into MFMA B-fragment order ---------------------
__global__ __launch_bounds__(64)
void k_wprep(const float* __restrict__ W, short* __restrict__ frag,
             int nct_total, int ct0, int nct) {
  const int b = blockIdx.x;
  const int kt = b / nct, ct = b % nct;
  const int l = threadIdx.x;
  const int c = ct * 16 + (l & 15);
  const int k0 = kt * 32 + (l >> 4) * 8;
  short* dst = frag + ((size_t)(kt * nct_total + ct0 + ct) * 64 + l) * 8;
#pragma unroll
  for (int i = 0; i < 8; ++i) dst[i] = f2bf(W[(size_t)(k0 + i) * CF + c]);
}

// ---- effective relation weights: Wk@blockdiag(att), Wv@blockdiag(msg) --------
__global__ __launch_bounds__(64)
void k_wrel(const float* __restrict__ Wk, const float* __restrict__ Wv,
            const float* __restrict__ rel_att, const float* __restrict__ rel_msg,
            short* __restrict__ wfragBig) {
  const int b = blockIdx.x;              // 128 = 4 mats * 4 kt * 8 hh
  const int mat = b >> 5, kt = (b >> 3) & 3, hh = b & 7;
  const int rel = mat >> 1, typ = mat & 1;
  const float* W   = typ ? Wv : Wk;
  const float* att = typ ? rel_msg : rel_att;
  const int l = threadIdx.x;
  const int d = l & 15, k0 = kt * 32 + (l >> 4) * 8;
  float a[16];
#pragma unroll
  for (int jj = 0; jj < 16; ++jj) a[jj] = att[((rel * NH + hh) * 16 + jj) * 16 + d];
  const int ctg = 8 + rel * 16 + typ * 8 + hh;
  short* dst = wfragBig + ((size_t)(kt * 40 + ctg) * 64 + l) * 8;
#pragma unroll
  for (int i = 0; i < 8; ++i) {
    float v = 0.f;
#pragma unroll
    for (int jj = 0; jj < 16; ++jj)
      v = fmaf(W[(size_t)(k0 + i) * CF + hh * 16 + jj], a[jj], v);
    dst[i] = f2bf(v);
  }
}

// ---- effective relation biases -----------------------------------------------
__global__ void k_brel(const float* __restrict__ bk, const float* __restrict__ bv,
                       const float* __restrict__ rel_att, const float* __restrict__ rel_msg,
                       float* __restrict__ brel) {
  const int t = threadIdx.x;             // 512
  const int mat = t >> 7, c = t & 127, hh = c >> 4, d = c & 15;
  const int rel = mat >> 1, typ = mat & 1;
  const float* b   = typ ? bv : bk;
  const float* att = typ ? rel_msg : rel_att;
  float v = 0.f;
#pragma unroll
  for (int jj = 0; jj < 16; ++jj)
    v = fmaf(b[hh * 16 + jj], att[((rel * NH + hh) * 16 + jj) * 16 + d], v);
  brel[t] = v;
}

// ---- single MFMA projection: [q | kr0 | vr0 | kr1 | vr1] = h @ Wbig ----------
// 64 nodes/block, 4 waves; wave w owns heads {2w,2w+1} for all rel outputs.
__global__ __launch_bounds__(256)
void k_projm(const float* __restrict__ h, const short* __restrict__ wfragBig,
             const float* __restrict__ bq, const float* __restrict__ brel,
             float* __restrict__ q_out, uint4* __restrict__ krv0,
             uint4* __restrict__ krv1) {
  __shared__ __align__(16) short ldsA[BM * 136];
  __shared__ __align__(16) short ldsS[4][BM * 64];
  const int n0 = blockIdx.x * BM;
  const int t = threadIdx.x, w = t >> 6, l = t & 63;
  const int cl = l & 15, rg = (l >> 4) * 4, koff = (l >> 4) * 8;

  for (int idx = t; idx < BM * 32; idx += 256) {
    const int r = idx >> 5, c4 = idx & 31;
    float4 hv = make_float4(0.f, 0.f, 0.f, 0.f);
    if (n0 + r < NN) hv = *(const float4*)(h + (size_t)(n0 + r) * CF + c4 * 4);
    short* d = ldsA + r * 136 + c4 * 4;
    d[0] = f2bf(hv.x); d[1] = f2bf(hv.y); d[2] = f2bf(hv.z); d[3] = f2bf(hv.w);
  }
  __syncthreads();

  short8v af[4][4];
#pragma unroll
  for (int kt = 0; kt < 4; ++kt)
#pragma unroll
    for (int rt = 0; rt < 4; ++rt)
      af[kt][rt] = *(const short8v*)(ldsA + (rt * 16 + cl) * 136 + kt * 32 + koff);

  // q columns (ct 0..7)
#pragma unroll
  for (int qi = 0; qi < 2; ++qi) {
    const int ctg = 2 * w + qi;
    f32x4 acc[4] = {};
#pragma unroll
    for (int kt = 0; kt < 4; ++kt) {
      const short8v bf = *(const short8v*)(wfragBig + ((size_t)(kt * 40 + ctg) * 64 + l) * 8);
#pragma unroll
      for (int rt = 0; rt < 4; ++rt)
        acc[rt] = __builtin_amdgcn_mfma_f32_16x16x32_bf16(af[kt][rt], bf, acc[rt], 0, 0, 0);
    }
    const int c = ctg * 16 + cl;
    const float bias = bq[c];
#pragma unroll
    for (int rt = 0; rt < 4; ++rt)
#pragma unroll
      for (int r = 0; r < 4; ++r) {
        const int row = rt * 16 + rg + r;
        if (n0 + row < NN) q_out[(size_t)(n0 + row) * CF + c] = acc[rt][r] + bias;
      }
  }

  // relation outputs: kr/vr, staged per-wave then packed 16B stores
  for (int rel = 0; rel < 2; ++rel) {
#pragma unroll
    for (int typ = 0; typ < 2; ++typ) {
#pragma unroll
      for (int hi = 0; hi < 2; ++hi) {
        const int hh = 2 * w + hi;
        const int ctg = 8 + rel * 16 + typ * 8 + hh;
        f32x4 acc[4] = {};
#pragma unroll
        for (int kt = 0; kt < 4; ++kt) {
          const short8v bf = *(const short8v*)(wfragBig + ((size_t)(kt * 40 + ctg) * 64 + l) * 8);
#pragma unroll
          for (int rt = 0; rt < 4; ++rt)
            acc[rt] = __builtin_amdgcn_mfma_f32_16x16x32_bf16(af[kt][rt], bf, acc[rt], 0, 0, 0);
        }
        const int c = hh * 16 + cl;
        const float bias = brel[(rel * 2 + typ) * CF + c];
#pragma unroll
        for (int rt = 0; rt < 4; ++rt)
#pragma unroll
          for (int r = 0; r < 4; ++r) {
            const int row = rt * 16 + rg + r;
            ldsS[w][row * 64 + hi * 32 + (cl >> 2) * 8 + typ * 4 + (cl & 3)] =
                f2bf(acc[rt][r] + bias);
          }
      }
    }
    __syncthreads();
    uint4* krv = rel ? krv1 : krv0;
#pragma unroll
    for (int i = 0; i < 8; ++i) {
      const int m = i * 64 + l;            // 0..511
      const int row = m >> 3, ent = m & 7, hl = ent >> 2, dq = ent & 3;
      if (n0 + row < NN)
        krv[(size_t)(n0 + row) * 32 + (2 * w + hl) * 4 + dq] =
            *(const uint4*)(ldsS[w] + row * 64 + hl * 32 + dq * 8);
    }
    __syncthreads();
  }
}

// ---- CSR build (both relations, concatenated index space) --------------------
__global__ __launch_bounds__(256)
void k_count2(const int* __restrict__ dst0, const int* __restrict__ dst1,
              int* __restrict__ deg2) {
  const int e = blockIdx.x * 256 + threadIdx.x;
  if (e < EE) atomicAdd(&deg2[dst0[e]], 1);
  else if (e < 2 * EE) atomicAdd(&deg2[NN + dst1[e - EE]], 1);
}

__global__ __launch_bounds__(1024)
void k_scan1(const int* __restrict__ deg, int* __restrict__ rowptr,
             int* __restrict__ bsum, int n) {
  __shared__ int wsum[16];
  const int i = blockIdx.x * 1024 + threadIdx.x;
  const int lane = threadIdx.x & 63, w = threadIdx.x >> 6;
  const int vdeg = (i < n) ? deg[i] : 0;
  int sc = vdeg;
  for (int off = 1; off < 64; off <<= 1) {
    const int x = __shfl_up(sc, off, 64);
    if (lane >= off) sc += x;
  }
  if (lane == 63) wsum[w] = sc;
  __syncthreads();
  if (threadIdx.x < 16) {
    const int x = wsum[threadIdx.x];
    int s2 = x;
    for (int off = 1; off < 16; off <<= 1) {
      const int y = __shfl_up(s2, off, 64);
      if ((int)threadIdx.x >= off) s2 += y;
    }
    wsum[threadIdx.x] = s2 - x;
    if (threadIdx.x == 15) bsum[blockIdx.x] = s2;
  }
  __syncthreads();
  if (i < n) rowptr[i] = sc - vdeg + wsum[w];
}

__global__ __launch_bounds__(128)
void k_scan2(int* __restrict__ bsum, int nb) {
  __shared__ int tmp[128];
  const int t = threadIdx.x;
  const int v = (t < nb) ? bsum[t] : 0;
  tmp[t] = v;
  __syncthreads();
  for (int off = 1; off < 128; off <<= 1) {
    const int x = (t >= off) ? tmp[t - off] : 0;
    __syncthreads();
    tmp[t] += x;
    __syncthreads();
  }
  if (t < nb) bsum[t] = tmp[t] - v;
}

__global__ __launch_bounds__(1024)
void k_scan3(int* __restrict__ rowptr, const int* __restrict__ bsum,
             int* __restrict__ cursor, int n, int total) {
  const int i = blockIdx.x * 1024 + threadIdx.x;
  if (i < n) {
    const int vv = rowptr[i] + bsum[blockIdx.x];
    rowptr[i] = vv;
    cursor[i] = vv;
  } else if (i == n) {
    rowptr[n] = total;
  }
}

__global__ __launch_bounds__(256)
void k_fill2(const int* __restrict__ src0, const int* __restrict__ dst0,
             const int* __restrict__ src1, const int* __restrict__ dst1,
             int* __restrict__ cursor, int* __restrict__ esrc) {
  const int e = blockIdx.x * 256 + threadIdx.x;
  if (e < EE) {
    const int pos = atomicAdd(&cursor[dst0[e]], 1);
    esrc[pos] = src0[e];
  } else if (e < 2 * EE) {
    const int pos = atomicAdd(&cursor[NN + dst1[e - EE]], 1);
    esrc[pos] = src1[e - EE];
  }
}

// ---- attention aggregate: 1 node/block, 8 edge streams -----------------------
// lane = (sid=t>>5)*? : sl = t&31 -> head hh=sl>>2, dims dq*4..+3; one uint4 per edge.
__global__ __launch_bounds__(256)
void k_att(const float* __restrict__ q,
           const uint4* __restrict__ krv0, const uint4* __restrict__ krv1,
           const int* __restrict__ rowptrC, const int* __restrict__ esrcC,
           const float* __restrict__ rel_pri, float* __restrict__ t_agg) {
  __shared__ __align__(16) float4 raccS[8][32];
  __shared__ float sdenS[8][32];
  const int n = blockIdx.x, t = threadIdx.x;
  const int sid = t >> 5, sl = t & 31;
  const int hh = sl >> 2;
  const float4 qv = ((const float4*)(q + (size_t)n * CF))[sl];
  float4 acc = make_float4(0.f, 0.f, 0.f, 0.f);

  for (int rel = 0; rel < 2; ++rel) {
    const uint4* krv = rel ? krv1 : krv0;
    const int base = rel ? NN + n : n;
    const int e0 = rowptrC[base], e1 = rowptrC[base + 1];
    const float pri = rel_pri[rel * NH + hh] * 0.25f;  // 1/sqrt(16)
    float4 racc = make_float4(0.f, 0.f, 0.f, 0.f);
    float sden = 0.f;
    int e = e0 + sid;
    uint4 A = make_uint4(0, 0, 0, 0), B = make_uint4(0, 0, 0, 0);
    if (e < e1) A = krv[(size_t)esrcC[e] * 32 + sl];
    if (e + 8 < e1) B = krv[(size_t)esrcC[e + 8] * 32 + sl];
    for (; e < e1; e += 8) {
      const uint4 C = A;
      A = B;
      if (e + 16 < e1) B = krv[(size_t)esrcC[e + 16] * 32 + sl];
      float sc = fmaf(qv.x, bf16lo(C.x),
                 fmaf(qv.y, bf16hi(C.x),
                 fmaf(qv.z, bf16lo(C.y), qv.w * bf16hi(C.y))));
      sc += __shfl_xor(sc, 1, 64);
      sc += __shfl_xor(sc, 2, 64);
      const float ex = __expf(sc * pri);
      sden += ex;
      racc.x = fmaf(bf16lo(C.z), ex, racc.x);
      racc.y = fmaf(bf16hi(C.z), ex, racc.y);
      racc.z = fmaf(bf16lo(C.w), ex, racc.z);
      racc.w = fmaf(bf16hi(C.w), ex, racc.w);
    }
    raccS[sid][sl] = racc;
    sdenS[sid][sl] = sden;
    __syncthreads();
    if (t < 32) {
      float4 rs = make_float4(0.f, 0.f, 0.f, 0.f);
      float ss = 0.f;
#pragma unroll
      for (int s = 0; s < 8; ++s) {
        const float4 rv = raccS[s][t];
        rs.x += rv.x; rs.y += rv.y; rs.z += rv.z; rs.w += rv.w;
        ss += sdenS[s][t];
      }
      if (ss > 0.f) {
        const float inv = 1.f / ss;
        acc.x = fmaf(rs.x, inv, acc.x);
        acc.y = fmaf(rs.y, inv, acc.y);
        acc.z = fmaf(rs.z, inv, acc.z);
        acc.w = fmaf(rs.w, inv, acc.w);
      }
    }
    __syncthreads();
  }
  if (t < 32) ((float4*)(t_agg + (size_t)n * CF))[t] = acc;
}

// ---- MFMA MLP: GELU(t_agg) @ Wa + ba, skip blend -----------------------------
__global__ __launch_bounds__(256)
void k_mlpm(const float* __restrict__ t_agg, const float* __restrict__ h,
            const short* __restrict__ wafrag, const float* __restrict__ ba,
            const float* __restrict__ skip, float* __restrict__ out) {
  __shared__ __align__(16) short ldsA[BM * 136];
  const int n0 = blockIdx.x * BM;
  const int t = threadIdx.x;
  const int w = t >> 6, l = t & 63;

  for (int idx = t; idx < BM * 32; idx += 256) {
    const int r = idx >> 5, c4 = idx & 31;
    float4 x = make_float4(0.f, 0.f, 0.f, 0.f);
    if (n0 + r < NN) x = *(const float4*)(t_agg + (size_t)(n0 + r) * CF + c4 * 4);
    short* d = ldsA + r * 136 + c4 * 4;
    d[0] = f2bf(0.5f * x.x * (1.f + erff(x.x * 0.70710678118f)));
    d[1] = f2bf(0.5f * x.y * (1.f + erff(x.y * 0.70710678118f)));
    d[2] = f2bf(0.5f * x.z * (1.f + erff(x.z * 0.70710678118f)));
    d[3] = f2bf(0.5f * x.w * (1.f + erff(x.w * 0.70710678118f)));
  }
  __syncthreads();

  f32x4 acc[4][2] = {};
#pragma unroll
  for (int kt = 0; kt < 4; ++kt) {
    const int ko = kt * 32 + (l >> 4) * 8;
    short8v af[4];
#pragma unroll
    for (int rt = 0; rt < 4; ++rt)
      af[rt] = *(const short8v*)(ldsA + (rt * 16 + (l & 15)) * 136 + ko);
#pragma unroll
    for (int cti = 0; cti < 2; ++cti) {
      const int ct = w * 2 + cti;
      const short8v bf = *(const short8v*)(wafrag + (((size_t)(kt * 8 + ct)) * 64 + l) * 8);
#pragma unroll
      for (int rt = 0; rt < 4; ++rt)
        acc[rt][cti] = __builtin_amdgcn_mfma_f32_16x16x32_bf16(af[rt], bf, acc[rt][cti], 0, 0, 0);
    }
  }

  const float alpha = 1.f / (1.f + __expf(-skip[0]));
  const int cl = l & 15, rg = (l >> 4) * 4;
#pragma unroll
  for (int cti = 0; cti < 2; ++cti) {
    const int c = (w * 2 + cti) * 16 + cl;
    const float bias = ba[c];
#pragma unroll
    for (int rt = 0; rt < 4; ++rt) {
#pragma unroll
      for (int r = 0; r < 4; ++r) {
        const int row = rt * 16 + rg + r;
        if (n0 + row < NN)
          out[(size_t)(n0 + row) * CF + c] =
              (acc[rt][cti][r] + bias) * alpha + h[(size_t)(n0 + row) * CF + c] * (1.f - alpha);
      }
    }
  }
}

extern "C" void kernel_launch(void* const* d_in, const int* in_sizes, int n_in,
                              void* d_out, int out_size, void* d_ws, size_t ws_size,
                              hipStream_t stream) {
  const float* h = (const float*)d_in[0];
  const int* src0 = (const int*)d_in[1];
  const int* dst0 = (const int*)d_in[2];
  const int* src1 = (const int*)d_in[3];
  const int* dst1 = (const int*)d_in[4];
  const float* Wk = (const float*)d_in[5],  *bk = (const float*)d_in[6];
  const float* Wq = (const float*)d_in[7],  *bq = (const float*)d_in[8];
  const float* Wv = (const float*)d_in[9],  *bv = (const float*)d_in[10];
  const float* Wa = (const float*)d_in[11], *ba = (const float*)d_in[12];
  const float* rel_att = (const float*)d_in[13];
  const float* rel_msg = (const float*)d_in[14];
  const float* rel_pri = (const float*)d_in[15];
  const float* skip    = (const float*)d_in[16];
  float* out = (float*)d_out;

  const size_t NC = (size_t)NN * CF;
  float* q     = (float*)d_ws;
  float* t_agg = q + NC;
  float* brel  = t_agg + NC;                 // 512 f32
  uint4* krv0  = (uint4*)(brel + 512);       // N*32 uint4
  uint4* krv1  = krv0 + (size_t)NN * 32;
  short* wfragBig = (short*)(krv1 + (size_t)NN * 32);  // 4*40*64*8
  short* wfragA   = wfragBig + 4 * 40 * 64 * 8;        // 4*8*64*8
  int* ip = (int*)(wfragA + 4 * 8 * 64 * 8);
  int* rowptrC = ip;
  int* esrcC   = rowptrC + 2 * NN + 2;
  int* deg2    = esrcC + 2 * EE;
  int* cursor  = deg2 + 2 * NN;
  int* bsum    = cursor + 2 * NN;

  k_wprep<<<32, 64, 0, stream>>>(Wq, wfragBig, 40, 0, 8);
  k_wprep<<<32, 64, 0, stream>>>(Wa, wfragA, 8, 0, 8);
  k_wrel<<<128, 64, 0, stream>>>(Wk, Wv, rel_att, rel_msg, wfragBig);
  k_brel<<<1, 512, 0, stream>>>(bk, bv, rel_att, rel_msg, brel);

  const int mgrid = (NN + BM - 1) / BM;  // 782
  k_projm<<<mgrid, 256, 0, stream>>>(h, wfragBig, bq, brel, q, krv0, krv1);

  const int egrid2 = (2 * EE + 255) / 256;
  const int n2 = 2 * NN;
  const int nb = (n2 + 1023) / 1024;
  const int nb3 = (n2 + 1 + 1023) / 1024;
  hipMemsetAsync(deg2, 0, n2 * sizeof(int), stream);
  k_count2<<<egrid2, 256, 0, stream>>>(dst0, dst1, deg2);
  k_scan1<<<nb, 1024, 0, stream>>>(deg2, rowptrC, bsum, n2);
  k_scan2<<<1, 128, 0, stream>>>(bsum, nb);
  k_scan3<<<nb3, 1024, 0, stream>>>(rowptrC, bsum, cursor, n2, 2 * EE);
  k_fill2<<<egrid2, 256, 0, stream>>>(src0, dst0, src1, dst1, cursor, esrcC);

  k_att<<<NN, 256, 0, stream>>>(q, krv0, krv1, rowptrC, esrcC, rel_pri, t_agg);
  k_mlpm<<<mgrid, 256, 0, stream>>>(t_agg, h, wfragA, ba, skip, out);
}